// Round 4
// baseline (1179.209 us; speedup 1.0000x reference)
//
#include <hip/hip_runtime.h>
#include <hip/hip_bf16.h>

#define T_ 1024
#define D_ 2048
#define E_ 16
#define K_ 4
#define F_ 768
#define NR_ (T_*K_)   // 4096 compact token-expert rows total

typedef __attribute__((ext_vector_type(8))) short bf16x8;
typedef __attribute__((ext_vector_type(16))) float f32x16;

__device__ __forceinline__ unsigned short bf16_rne(float f) {
    unsigned int u = __float_as_uint(f);
    u += 0x7fffu + ((u >> 16) & 1u);
    return (unsigned short)(u >> 16);
}
__device__ __forceinline__ float bf16f(unsigned short h) {
    return __uint_as_float(((unsigned int)h) << 16);
}

// ---------------- Router: logits -> softmax -> top4 -> normalized weights ----
__global__ __launch_bounds__(64) void router_kernel(
    const float* __restrict__ x, const float* __restrict__ gw,
    int* __restrict__ topk_idx, float* __restrict__ topk_w)
{
    int t = blockIdx.x;
    int lane = threadIdx.x;
    float acc[E_];
#pragma unroll
    for (int e = 0; e < E_; ++e) acc[e] = 0.f;
    const float* xr = x + (size_t)t * D_;
    for (int d = lane; d < D_; d += 64) {
        float xv = xr[d];
        const float4* g4 = (const float4*)(gw + (size_t)d * E_);
#pragma unroll
        for (int q = 0; q < 4; ++q) {
            float4 g = g4[q];
            acc[q*4+0] = fmaf(xv, g.x, acc[q*4+0]);
            acc[q*4+1] = fmaf(xv, g.y, acc[q*4+1]);
            acc[q*4+2] = fmaf(xv, g.z, acc[q*4+2]);
            acc[q*4+3] = fmaf(xv, g.w, acc[q*4+3]);
        }
    }
#pragma unroll
    for (int e = 0; e < E_; ++e) {
#pragma unroll
        for (int off = 32; off; off >>= 1) acc[e] += __shfl_xor(acc[e], off);
    }
    if (lane == 0) {
        float mx = acc[0];
#pragma unroll
        for (int e = 1; e < E_; ++e) mx = fmaxf(mx, acc[e]);
        float p[E_];
#pragma unroll
        for (int e = 0; e < E_; ++e) p[e] = expf(acc[e] - mx);
        float wsum = 0.f;
        int   bidx[K_]; float bval[K_];
        for (int k = 0; k < K_; ++k) {
            int bi = 0; float bv = -1.f;
            for (int e = 0; e < E_; ++e) {
                if (p[e] > bv) { bv = p[e]; bi = e; }
            }
            bidx[k] = bi; bval[k] = bv; wsum += bv; p[bi] = -2.f;
        }
        float inv = 1.f / wsum;
        for (int k = 0; k < K_; ++k) {
            topk_idx[t*K_ + k] = bidx[k];
            topk_w[t*K_ + k]   = bval[k] * inv;
        }
    }
}

// ---------------- Bucket: count/prefix/compact (single block) ----------------
__global__ __launch_bounds__(256) void bucket_kernel(
    const int* __restrict__ topk_idx, const float* __restrict__ topk_w,
    int* __restrict__ cnt, int* __restrict__ off,
    int* __restrict__ row_token, float* __restrict__ row_w,
    int* __restrict__ pair2row)
{
    __shared__ int c1[E_], c2[E_], so[E_];
    int tid = threadIdx.x;
    if (tid < E_) { c1[tid] = 0; c2[tid] = 0; }
    __syncthreads();
    for (int p = tid; p < T_*K_; p += 256) atomicAdd(&c1[topk_idx[p]], 1);
    __syncthreads();
    if (tid == 0) {
        int o = 0;
        for (int e = 0; e < E_; ++e) { so[e] = o; off[e] = o; cnt[e] = c1[e]; o += c1[e]; }
    }
    __syncthreads();
    for (int p = tid; p < T_*K_; p += 256) {
        int e = topk_idx[p];
        int pos = so[e] + atomicAdd(&c2[e], 1);
        row_token[pos] = p >> 2;
        row_w[pos]     = topk_w[p];
        pair2row[p]    = pos;
    }
}

// ---------------- Grouped GEMM, split-bf16 3-term MFMA -----------------------
// MODE 0: C[r][n] = sum_k x[row_token[r]][k] * wgu[e][k][n]   (K=2048, N=1536)
// MODE 1: C[r][n] = row_w[r] * sum_k h[r][k]  * wd[e][k][n]   (K=768,  N=2048)
// Block: 256 rows x 128 cols, BK=32, 512 threads (8 waves, wave = 64x64).
// 1D grid, work index w = (e*NY + y)*4 + rt  (rt innermost: the 4 row-tile
// siblings sharing a B panel are adjacent), chunk-mapped to XCDs (T1, exact
// since gridDim%8==0) so siblings co-locate on one XCD's L2.
template<int MODE>
__global__ __launch_bounds__(512, 2) void moe_gemm(
    const float* __restrict__ A,
    const float* __restrict__ B,
    const int* __restrict__ cnt, const int* __restrict__ off,
    const int* __restrict__ row_token, const float* __restrict__ row_w,
    float* __restrict__ C)
{
    constexpr int KT = MODE ? F_  : D_;
    constexpr int NT = MODE ? D_  : 2*F_;
    constexpr int NY = NT / 128;

    const int G = gridDim.x;              // 64*NY, divisible by 8
    const int b = blockIdx.x;
    const int w0 = (b & 7) * (G >> 3) + (b >> 3);   // bijective XCD chunk map
    const int rt  = w0 & 3;
    const int grp = w0 >> 2;
    const int e   = grp / NY;
    const int n0  = (grp % NY) * 128;

    const int n = cnt[e];
    if (rt * 256 >= n) return;
    const int base = off[e];

    // split-bf16 planes; element (row,k) at ushort idx (row*32+k) ^ ((row&7)<<3)
    __shared__ unsigned short Ah[256*32];
    __shared__ unsigned short Al[256*32];
    __shared__ unsigned short Bh[128*32];
    __shared__ unsigned short Bl[128*32];

    const int tid = threadIdx.x;

    // A staging: thread -> row tid>>1, k-half (tid&1)*16, 4 float4s
    const int s_row = tid >> 1;
    const int s_kc  = (tid & 1) << 4;
    const int rl = min(rt*256 + s_row, n - 1);
    const float* arow;
    if (MODE == 0) arow = A + (size_t)row_token[base + rl] * D_;
    else           arow = A + (size_t)(base + rl) * F_;

    // B staging: thread -> cols (tid&31)*4 .. +3, k rows (tid>>5)*2, +1
    const int b_c4 = (tid & 31) << 2;
    const int b_kg = (tid >> 5) << 1;
    const float* bptr = B + (size_t)e * KT * NT + n0 + b_c4;

    // compute mapping: 8 waves in 4x2 grid, each wave 64x64 = 2x2 tiles of 32x32
    const int lane = tid & 63;
    const int wv   = tid >> 6;
    const int wr   = wv >> 1;    // 0..3
    const int wc   = wv & 1;     // 0..1
    const int lrow = lane & 31;
    const int lhi  = lane >> 5;  // 0|1

    f32x16 acc[2][2] = {};

    for (int k0 = 0; k0 < KT; k0 += 32) {
        // ---- stage A (256x32) as hi/lo bf16 planes
        {
            const float* p = arow + k0 + s_kc;
#pragma unroll
            for (int i = 0; i < 4; ++i) {
                float4 v = *(const float4*)(p + i*4);
                unsigned short h0 = bf16_rne(v.x), h1 = bf16_rne(v.y),
                               h2 = bf16_rne(v.z), h3 = bf16_rne(v.w);
                unsigned short l0 = bf16_rne(v.x - bf16f(h0)),
                               l1 = bf16_rne(v.y - bf16f(h1)),
                               l2 = bf16_rne(v.z - bf16f(h2)),
                               l3 = bf16_rne(v.w - bf16f(h3));
                int u = ((s_row << 5) + s_kc + i*4) ^ ((s_row & 7) << 3);
                *(ushort4*)&Ah[u] = make_ushort4(h0, h1, h2, h3);
                *(ushort4*)&Al[u] = make_ushort4(l0, l1, l2, l3);
            }
        }
        // ---- stage B (32x128) transposed to [col][k] hi/lo planes
        {
            const float* p0 = bptr + (size_t)(k0 + b_kg) * NT;
            float4 v0 = *(const float4*)p0;
            float4 v1 = *(const float4*)(p0 + NT);
            float va0[4] = {v0.x, v0.y, v0.z, v0.w};
            float va1[4] = {v1.x, v1.y, v1.z, v1.w};
#pragma unroll
            for (int c = 0; c < 4; ++c) {
                unsigned short h0 = bf16_rne(va0[c]), h1 = bf16_rne(va1[c]);
                unsigned short L0 = bf16_rne(va0[c] - bf16f(h0)),
                               L1 = bf16_rne(va1[c] - bf16f(h1));
                int col = b_c4 + c;
                int u = ((col << 5) + b_kg) ^ ((col & 7) << 3);
                *(unsigned int*)&Bh[u] = (unsigned int)h0 | ((unsigned int)h1 << 16);
                *(unsigned int*)&Bl[u] = (unsigned int)L0 | ((unsigned int)L1 << 16);
            }
        }
        __syncthreads();

        // ---- 2 k-substeps x (2x2 tiles) x 3 split terms
#pragma unroll
        for (int kb = 0; kb < 2; ++kb) {
            const int koff = kb*16 + lhi*8;
            bf16x8 fah[2], fal[2], fbh[2], fbl[2];
#pragma unroll
            for (int mt = 0; mt < 2; ++mt) {
                int row = wr*64 + mt*32 + lrow;
                int u = ((row << 5) + koff) ^ ((row & 7) << 3);
                fah[mt] = *(const bf16x8*)&Ah[u];
                fal[mt] = *(const bf16x8*)&Al[u];
            }
#pragma unroll
            for (int nt = 0; nt < 2; ++nt) {
                int col = wc*64 + nt*32 + lrow;
                int u = ((col << 5) + koff) ^ ((col & 7) << 3);
                fbh[nt] = *(const bf16x8*)&Bh[u];
                fbl[nt] = *(const bf16x8*)&Bl[u];
            }
#pragma unroll
            for (int mt = 0; mt < 2; ++mt)
#pragma unroll
                for (int nt = 0; nt < 2; ++nt) {
                    acc[mt][nt] = __builtin_amdgcn_mfma_f32_32x32x16_bf16(fah[mt], fbh[nt], acc[mt][nt], 0, 0, 0);
                    acc[mt][nt] = __builtin_amdgcn_mfma_f32_32x32x16_bf16(fah[mt], fbl[nt], acc[mt][nt], 0, 0, 0);
                    acc[mt][nt] = __builtin_amdgcn_mfma_f32_32x32x16_bf16(fal[mt], fbh[nt], acc[mt][nt], 0, 0, 0);
                }
        }
        __syncthreads();
    }

    // ---- epilogue: C/D layout col=lane&31, row=(reg&3)+8*(reg>>2)+4*(lane>>5)
#pragma unroll
    for (int mt = 0; mt < 2; ++mt) {
#pragma unroll
        for (int r = 0; r < 16; ++r) {
            int row_d = (r & 3) + 8*(r >> 2) + 4*lhi;
            int R = rt*256 + wr*64 + mt*32 + row_d;
            if (R < n) {
                size_t crow = (size_t)(base + R) * NT + n0;
                float s = MODE ? row_w[base + R] : 1.0f;
#pragma unroll
                for (int nt = 0; nt < 2; ++nt)
                    C[crow + wc*64 + nt*32 + lrow] = acc[mt][nt][r] * s;
            }
        }
    }
}

// ---------------- SiLU(g) * u over compact gate_up ---------------------------
__global__ __launch_bounds__(256) void silu_mul_kernel(
    const float* __restrict__ gu, float* __restrict__ h)
{
    int idx = blockIdx.x * 256 + threadIdx.x;    // over NR_ * F_/4
    int r  = idx / (F_/4);
    int fc = (idx % (F_/4)) * 4;
    const float4 g = *(const float4*)(gu + (size_t)r * (2*F_) + fc);
    const float4 u = *(const float4*)(gu + (size_t)r * (2*F_) + F_ + fc);
    float4 o;
    o.x = g.x / (1.f + expf(-g.x)) * u.x;
    o.y = g.y / (1.f + expf(-g.y)) * u.y;
    o.z = g.z / (1.f + expf(-g.z)) * u.z;
    o.w = g.w / (1.f + expf(-g.w)) * u.w;
    *(float4*)(h + (size_t)r * F_ + fc) = o;
}

// ---------------- Combine: out[t] = sum_k eo[pair2row[t,k]] ------------------
__global__ __launch_bounds__(256) void combine_kernel(
    const float* __restrict__ eo, const int* __restrict__ pair2row,
    float* __restrict__ out)
{
    int idx = blockIdx.x * 256 + threadIdx.x;   // float4 index
    int t  = idx / (D_/4);
    int dc = idx % (D_/4);
    const int* pr = pair2row + t * K_;
    float4 s = {0.f, 0.f, 0.f, 0.f};
#pragma unroll
    for (int k = 0; k < K_; ++k) {
        float4 v = *(const float4*)(eo + (size_t)pr[k] * D_ + (size_t)dc * 4);
        s.x += v.x; s.y += v.y; s.z += v.z; s.w += v.w;
    }
    *(float4*)(out + (size_t)t * D_ + (size_t)dc * 4) = s;
}

extern "C" void kernel_launch(void* const* d_in, const int* in_sizes, int n_in,
                              void* d_out, int out_size, void* d_ws, size_t ws_size,
                              hipStream_t stream)
{
    (void)in_sizes; (void)n_in; (void)out_size; (void)ws_size;
    const float* x   = (const float*)d_in[0];   // (T, D)
    const float* gw  = (const float*)d_in[1];   // (D, E)
    const float* wgu = (const float*)d_in[2];   // (E, D, 2F)
    const float* wd  = (const float*)d_in[3];   // (E, F, D)
    float* out = (float*)d_out;                 // (T, D)

    char* w = (char*)d_ws;
    int*   topk_idx  = (int*)w;   w += (size_t)T_*K_*4;
    float* topk_w    = (float*)w; w += (size_t)T_*K_*4;
    int*   cnt       = (int*)w;   w += 64*4;
    int*   off       = (int*)w;   w += 64*4;
    int*   row_token = (int*)w;   w += (size_t)T_*K_*4;
    float* row_w     = (float*)w; w += (size_t)T_*K_*4;
    int*   pair2row  = (int*)w;   w += (size_t)T_*K_*4;
    uintptr_t up = ((uintptr_t)w + 255) & ~(uintptr_t)255;
    w = (char*)up;
    float* gu = (float*)w; w += (size_t)NR_*(2*F_)*4;  // 25.2 MB
    float* h  = (float*)w; w += (size_t)NR_*F_*4;      // 12.6 MB
    float* eo = (float*)w; w += (size_t)NR_*D_*4;      // 33.6 MB

    router_kernel<<<T_, 64, 0, stream>>>(x, gw, topk_idx, topk_w);
    bucket_kernel<<<1, 256, 0, stream>>>(topk_idx, topk_w, cnt, off,
                                         row_token, row_w, pair2row);
    moe_gemm<0><<<64 * ((2*F_)/128), 512, 0, stream>>>(
        x, wgu, cnt, off, row_token, row_w, gu);
    silu_mul_kernel<<<(NR_*(F_/4))/256, 256, 0, stream>>>(gu, h);
    moe_gemm<1><<<64 * (D_/128), 512, 0, stream>>>(
        h, wd, cnt, off, row_token, row_w, eo);
    combine_kernel<<<(T_*D_/4)/256, 256, 0, stream>>>(eo, pair2row, out);
}

// Round 7
// 580.105 us; speedup vs baseline: 2.0328x; 2.0328x over previous
//
#include <hip/hip_runtime.h>
#include <hip/hip_bf16.h>

#define T_ 1024
#define D_ 2048
#define E_ 16
#define K_ 4
#define F_ 768
#define NR_ (T_*K_)   // 4096 compact token-expert pair rows

typedef __attribute__((ext_vector_type(8))) short bf16x8;
typedef __attribute__((ext_vector_type(16))) float f32x16;

union V8 { uint4 u; bf16x8 v; };

// fp32 -> (hi = rne-bf16, lo = rne-bf16 of residual). Same numerics as the
// round-4 PASS (absmax 0.0078). Compiler pairs __float2bfloat16 into
// v_cvt_pk_bf16_f32 (m240) -> ~3.5 VALU ops/element.
__device__ __forceinline__ void split8(const float* __restrict__ f, uint4& hv, uint4& lv) {
    unsigned int hw[4], lw[4];
#pragma unroll
    for (int p = 0; p < 4; ++p) {
        union { __hip_bfloat16 b; unsigned short s; } h0, h1, l0, l1;
        h0.b = __float2bfloat16(f[2*p]);
        h1.b = __float2bfloat16(f[2*p+1]);
        float r0 = f[2*p]   - __uint_as_float((unsigned int)h0.s << 16);
        float r1 = f[2*p+1] - __uint_as_float((unsigned int)h1.s << 16);
        l0.b = __float2bfloat16(r0);
        l1.b = __float2bfloat16(r1);
        hw[p] = (unsigned int)h0.s | ((unsigned int)h1.s << 16);
        lw[p] = (unsigned int)l0.s | ((unsigned int)l1.s << 16);
    }
    hv = make_uint4(hw[0], hw[1], hw[2], hw[3]);
    lv = make_uint4(lw[0], lw[1], lw[2], lw[3]);
}

// ---------------- Router ------------------------------------------------------
__global__ __launch_bounds__(64) void router_kernel(
    const float* __restrict__ x, const float* __restrict__ gw,
    int* __restrict__ topk_idx, float* __restrict__ topk_w)
{
    int t = blockIdx.x;
    int lane = threadIdx.x;
    float acc[E_];
#pragma unroll
    for (int e = 0; e < E_; ++e) acc[e] = 0.f;
    const float* xr = x + (size_t)t * D_;
    for (int d = lane; d < D_; d += 64) {
        float xv = xr[d];
        const float4* g4 = (const float4*)(gw + (size_t)d * E_);
#pragma unroll
        for (int q = 0; q < 4; ++q) {
            float4 g = g4[q];
            acc[q*4+0] = fmaf(xv, g.x, acc[q*4+0]);
            acc[q*4+1] = fmaf(xv, g.y, acc[q*4+1]);
            acc[q*4+2] = fmaf(xv, g.z, acc[q*4+2]);
            acc[q*4+3] = fmaf(xv, g.w, acc[q*4+3]);
        }
    }
#pragma unroll
    for (int e = 0; e < E_; ++e) {
#pragma unroll
        for (int off = 32; off; off >>= 1) acc[e] += __shfl_xor(acc[e], off);
    }
    if (lane == 0) {
        float mx = acc[0];
#pragma unroll
        for (int e = 1; e < E_; ++e) mx = fmaxf(mx, acc[e]);
        float p[E_];
#pragma unroll
        for (int e = 0; e < E_; ++e) p[e] = expf(acc[e] - mx);
        float wsum = 0.f;
        int   bidx[K_]; float bval[K_];
        for (int k = 0; k < K_; ++k) {
            int bi = 0; float bv = -1.f;
            for (int e = 0; e < E_; ++e) {
                if (p[e] > bv) { bv = p[e]; bi = e; }
            }
            bidx[k] = bi; bval[k] = bv; wsum += bv; p[bi] = -2.f;
        }
        float inv = 1.f / wsum;
        for (int k = 0; k < K_; ++k) {
            topk_idx[t*K_ + k] = bidx[k];
            topk_w[t*K_ + k]   = bval[k] * inv;
        }
    }
}

// ---------------- Bucket ------------------------------------------------------
__global__ __launch_bounds__(256) void bucket_kernel(
    const int* __restrict__ topk_idx, const float* __restrict__ topk_w,
    int* __restrict__ cnt, int* __restrict__ off,
    int* __restrict__ row_token, float* __restrict__ row_w,
    int* __restrict__ pair2row)
{
    __shared__ int c1[E_], c2[E_], so[E_];
    int tid = threadIdx.x;
    if (tid < E_) { c1[tid] = 0; c2[tid] = 0; }
    __syncthreads();
    for (int p = tid; p < T_*K_; p += 256) atomicAdd(&c1[topk_idx[p]], 1);
    __syncthreads();
    if (tid == 0) {
        int o = 0;
        for (int e = 0; e < E_; ++e) { so[e] = o; off[e] = o; cnt[e] = c1[e]; o += c1[e]; }
    }
    __syncthreads();
    for (int p = tid; p < T_*K_; p += 256) {
        int e = topk_idx[p];
        int pos = so[e] + atomicAdd(&c2[e], 1);
        row_token[pos] = p >> 2;
        row_w[pos]     = topk_w[p];
        pair2row[p]    = pos;
    }
}

// ---------------- Grouped GEMM, split-bf16 3-term MFMA -----------------------
// Tile: 128 rows x 128 cols, BK=32, 256 threads = 4 waves of 64x64.
// A: fragment-major LDS (conflict-free b128 write AND read), hi/lo planes.
// B: per-lane direct global fragment loads (no LDS, 128B-coalesced segments).
// Grid b = rt*(16*NY) + e*NY + y: rt-major so live blocks dispatch first;
// panel-sharing rt-siblings are 16*NY (192/256 ≡ 0 mod 8) apart -> same XCD
// under round-robin -> B panel L2-reuse.
// MODE 0: C cols = [64 gate | 64 up]; epilogue silu(g)*u via LDS -> h. NY=12.
// MODE 1: plain cols of wd; epilogue scales by row_w -> eo.          NY=16.
template<int MODE>
__global__ __launch_bounds__(256, 2) void moe_gemm(
    const float* __restrict__ A,
    const float* __restrict__ B,
    const int* __restrict__ cnt, const int* __restrict__ off,
    const int* __restrict__ row_token, const float* __restrict__ row_w,
    float* __restrict__ C)
{
    constexpr int KT = MODE ? F_ : D_;
    constexpr int NT = MODE ? D_ : 2*F_;
    constexpr int NY = MODE ? (D_/128) : (F_/64);

    const int b  = blockIdx.x;
    const int y  = b % NY;
    const int e  = (b / NY) & 15;
    const int rt = b / (NY * 16);      // rt-major: live blocks dispatch first
    const int n  = cnt[e];
    if (rt * 128 >= n) return;
    const int base = off[e];

    // A planes, fragment-major: [kchunk 0..3][row 0..127] of 8 bf16 (uint4)
    __shared__ uint4 Ah[4][128];
    __shared__ uint4 Al[4][128];
    __shared__ float u_lds[(MODE == 0) ? 2 : 1][64][64];

    const int tid  = threadIdx.x;
    const int lane = tid & 63;
    const int wv   = tid >> 6;
    const int rg   = wv >> 1;          // row-group 0..1 (64 rows)
    const int ct   = wv & 1;           // col-group 0..1 (64 cols)
    const int lrow = lane & 31;
    const int lhi  = lane >> 5;        // k-half selector

    // ---- staging ids: thread covers row r_s, k-chunk pair ch (16 floats)
    const int r_s = tid & 127;
    const int ch  = tid >> 7;          // 0|1
    const int rl  = min(rt*128 + r_s, n - 1);
    const float* arow = MODE ? (A + (size_t)(base + rl) * F_)
                             : (A + (size_t)row_token[base + rl] * D_);

    // ---- B per-lane fragment columns (2 nt tiles of 32)
    const float* Bbase = B + (size_t)e * KT * NT;
    int bcol0;
    if (MODE) { bcol0 = y*128 + ct*64 + lrow; }
    else      { bcol0 = (ct ? (F_ + y*64) : (y*64)) + lrow; }
    const int bcol1 = bcol0 + 32;

    f32x16 acc[2][2] = {};             // [mt][nt]

    // prologue: preload A regs for k0=0
    float a_reg[16];
    {
        const float* p = arow + ch*16;
#pragma unroll
        for (int i = 0; i < 4; ++i) {
            float4 v = *(const float4*)(p + i*4);
            a_reg[i*4+0] = v.x; a_reg[i*4+1] = v.y;
            a_reg[i*4+2] = v.z; a_reg[i*4+3] = v.w;
        }
    }

    for (int k0 = 0; k0 < KT; k0 += 32) {
        // ---- issue B fragment loads (per-lane; lanes 0..31 one 128B segment)
        float bfv[2][2][8];            // [kb][nt][j]
        {
            const float* bp = Bbase + (size_t)(k0 + lhi*8) * NT;
#pragma unroll
            for (int kb = 0; kb < 2; ++kb)
#pragma unroll
                for (int j = 0; j < 8; ++j) {
                    int kofs = (kb*16 + j) * NT;
                    bfv[kb][0][j] = bp[kofs + bcol0];
                    bfv[kb][1][j] = bp[kofs + bcol1];
                }
        }

        // ---- convert A regs -> split planes, store to LDS
        V8 h0, l0, h1, l1;
        split8(a_reg + 0, h0.u, l0.u);
        split8(a_reg + 8, h1.u, l1.u);
        __syncthreads();               // WAR: prior frag reads done
        Ah[ch*2+0][r_s] = h0.u;  Al[ch*2+0][r_s] = l0.u;
        Ah[ch*2+1][r_s] = h1.u;  Al[ch*2+1][r_s] = l1.u;

        // ---- prefetch next A k-slab into regs (hides under MFMA phase)
        if (k0 + 32 < KT) {
            const float* p = arow + (k0 + 32) + ch*16;
#pragma unroll
            for (int i = 0; i < 4; ++i) {
                float4 v = *(const float4*)(p + i*4);
                a_reg[i*4+0] = v.x; a_reg[i*4+1] = v.y;
                a_reg[i*4+2] = v.z; a_reg[i*4+3] = v.w;
            }
        }
        __syncthreads();               // RAW: LDS writes visible

        // ---- compute: 2 k-substeps x (2x2 tiles) x 3 split terms
#pragma unroll
        for (int kb = 0; kb < 2; ++kb) {
            V8 fah[2], fal[2];
#pragma unroll
            for (int mt = 0; mt < 2; ++mt) {
                int r = rg*64 + mt*32 + lrow;
                fah[mt].u = Ah[kb*2 + lhi][r];
                fal[mt].u = Al[kb*2 + lhi][r];
            }
#pragma unroll
            for (int nt = 0; nt < 2; ++nt) {
                V8 bh, bl;
                split8(bfv[kb][nt], bh.u, bl.u);
#pragma unroll
                for (int mt = 0; mt < 2; ++mt) {
                    acc[mt][nt] = __builtin_amdgcn_mfma_f32_32x32x16_bf16(fah[mt].v, bh.v, acc[mt][nt], 0, 0, 0);
                    acc[mt][nt] = __builtin_amdgcn_mfma_f32_32x32x16_bf16(fah[mt].v, bl.v, acc[mt][nt], 0, 0, 0);
                    acc[mt][nt] = __builtin_amdgcn_mfma_f32_32x32x16_bf16(fal[mt].v, bh.v, acc[mt][nt], 0, 0, 0);
                }
            }
        }
    }

    // ---- epilogue.  C/D frag: col = lane&31, row = (r&3) + 8*(r>>2) + 4*lhi
    if (MODE == 0) {
        // up waves (ct=1) publish u; gate waves (ct=0) compute silu(g)*u -> h
        if (ct == 1) {
#pragma unroll
            for (int mt = 0; mt < 2; ++mt)
#pragma unroll
                for (int r = 0; r < 16; ++r) {
                    int rowd = (r & 3) + 8*(r >> 2) + 4*lhi;
#pragma unroll
                    for (int nt = 0; nt < 2; ++nt)
                        u_lds[rg][mt*32 + rowd][nt*32 + lrow] = acc[mt][nt][r];
                }
        }
        __syncthreads();
        if (ct == 0) {
#pragma unroll
            for (int mt = 0; mt < 2; ++mt)
#pragma unroll
                for (int r = 0; r < 16; ++r) {
                    int rowd = (r & 3) + 8*(r >> 2) + 4*lhi;
                    int R = rt*128 + rg*64 + mt*32 + rowd;
                    if (R < n) {
#pragma unroll
                        for (int nt = 0; nt < 2; ++nt) {
                            float g = acc[mt][nt][r];
                            float u = u_lds[rg][mt*32 + rowd][nt*32 + lrow];
                            float s = g / (1.f + expf(-g)) * u;
                            C[(size_t)(base + R) * F_ + y*64 + nt*32 + lrow] = s;
                        }
                    }
                }
        }
    } else {
#pragma unroll
        for (int mt = 0; mt < 2; ++mt)
#pragma unroll
            for (int r = 0; r < 16; ++r) {
                int rowd = (r & 3) + 8*(r >> 2) + 4*lhi;
                int R = rt*128 + rg*64 + mt*32 + rowd;
                if (R < n) {
                    float w = row_w[base + R];
#pragma unroll
                    for (int nt = 0; nt < 2; ++nt)
                        C[(size_t)(base + R) * D_ + y*128 + ct*64 + nt*32 + lrow] = acc[mt][nt][r] * w;
                }
            }
    }
}

// ---------------- Combine: out[t] = sum_k eo[pair2row[t,k]] ------------------
__global__ __launch_bounds__(256) void combine_kernel(
    const float* __restrict__ eo, const int* __restrict__ pair2row,
    float* __restrict__ out)
{
    int idx = blockIdx.x * 256 + threadIdx.x;   // float4 index
    int t  = idx / (D_/4);
    int dc = idx % (D_/4);
    const int* pr = pair2row + t * K_;
    float4 s = {0.f, 0.f, 0.f, 0.f};
#pragma unroll
    for (int k = 0; k < K_; ++k) {
        float4 v = *(const float4*)(eo + (size_t)pr[k] * D_ + (size_t)dc * 4);
        s.x += v.x; s.y += v.y; s.z += v.z; s.w += v.w;
    }
    *(float4*)(out + (size_t)t * D_ + (size_t)dc * 4) = s;
}

extern "C" void kernel_launch(void* const* d_in, const int* in_sizes, int n_in,
                              void* d_out, int out_size, void* d_ws, size_t ws_size,
                              hipStream_t stream)
{
    (void)in_sizes; (void)n_in; (void)out_size; (void)ws_size;
    const float* x   = (const float*)d_in[0];   // (T, D)
    const float* gw  = (const float*)d_in[1];   // (D, E)
    const float* wgu = (const float*)d_in[2];   // (E, D, 2F)
    const float* wd  = (const float*)d_in[3];   // (E, F, D)
    float* out = (float*)d_out;                 // (T, D)

    char* w = (char*)d_ws;
    int*   topk_idx  = (int*)w;   w += (size_t)T_*K_*4;
    float* topk_w    = (float*)w; w += (size_t)T_*K_*4;
    int*   cnt       = (int*)w;   w += 64*4;
    int*   off       = (int*)w;   w += 64*4;
    int*   row_token = (int*)w;   w += (size_t)T_*K_*4;
    float* row_w     = (float*)w; w += (size_t)T_*K_*4;
    int*   pair2row  = (int*)w;   w += (size_t)T_*K_*4;
    uintptr_t up = ((uintptr_t)w + 255) & ~(uintptr_t)255;
    w = (char*)up;
    float* h  = (float*)w; w += (size_t)NR_*F_*4;      // 12.6 MB
    float* eo = (float*)w; w += (size_t)NR_*D_*4;      // 33.6 MB

    router_kernel<<<T_, 64, 0, stream>>>(x, gw, topk_idx, topk_w);
    bucket_kernel<<<1, 256, 0, stream>>>(topk_idx, topk_w, cnt, off,
                                         row_token, row_w, pair2row);
    moe_gemm<0><<<8 * 16 * (F_/64), 256, 0, stream>>>(
        x, wgu, cnt, off, row_token, row_w, h);
    moe_gemm<1><<<8 * 16 * (D_/128), 256, 0, stream>>>(
        h, wd, cnt, off, row_token, row_w, eo);
    combine_kernel<<<(T_*D_/4)/256, 256, 0, stream>>>(eo, pair2row, out);
}

// Round 10
// 531.117 us; speedup vs baseline: 2.2202x; 1.0922x over previous
//
#include <hip/hip_runtime.h>
#include <hip/hip_bf16.h>

#define T_ 1024
#define D_ 2048
#define E_ 16
#define K_ 4
#define F_ 768
#define NR_ (T_*K_)   // 4096 compact token-expert pair rows

typedef __attribute__((ext_vector_type(8))) short bf16x8;
typedef __attribute__((ext_vector_type(16))) float f32x16;

union V8 { uint4 u; bf16x8 v; };

// fp32 -> (hi = rne-bf16, lo = rne-bf16 of residual). Same numerics as the
// round-4/7 PASS (absmax 0.0078).
__device__ __forceinline__ void split8(const float* __restrict__ f, uint4& hv, uint4& lv) {
    unsigned int hw[4], lw[4];
#pragma unroll
    for (int p = 0; p < 4; ++p) {
        union { __hip_bfloat16 b; unsigned short s; } h0, h1, l0, l1;
        h0.b = __float2bfloat16(f[2*p]);
        h1.b = __float2bfloat16(f[2*p+1]);
        float r0 = f[2*p]   - __uint_as_float((unsigned int)h0.s << 16);
        float r1 = f[2*p+1] - __uint_as_float((unsigned int)h1.s << 16);
        l0.b = __float2bfloat16(r0);
        l1.b = __float2bfloat16(r1);
        hw[p] = (unsigned int)h0.s | ((unsigned int)h1.s << 16);
        lw[p] = (unsigned int)l0.s | ((unsigned int)l1.s << 16);
    }
    hv = make_uint4(hw[0], hw[1], hw[2], hw[3]);
    lv = make_uint4(lw[0], lw[1], lw[2], lw[3]);
}

// ---------------- Router ------------------------------------------------------
__global__ __launch_bounds__(64) void router_kernel(
    const float* __restrict__ x, const float* __restrict__ gw,
    int* __restrict__ topk_idx, float* __restrict__ topk_w)
{
    int t = blockIdx.x;
    int lane = threadIdx.x;
    float acc[E_];
#pragma unroll
    for (int e = 0; e < E_; ++e) acc[e] = 0.f;
    const float* xr = x + (size_t)t * D_;
    for (int d = lane; d < D_; d += 64) {
        float xv = xr[d];
        const float4* g4 = (const float4*)(gw + (size_t)d * E_);
#pragma unroll
        for (int q = 0; q < 4; ++q) {
            float4 g = g4[q];
            acc[q*4+0] = fmaf(xv, g.x, acc[q*4+0]);
            acc[q*4+1] = fmaf(xv, g.y, acc[q*4+1]);
            acc[q*4+2] = fmaf(xv, g.z, acc[q*4+2]);
            acc[q*4+3] = fmaf(xv, g.w, acc[q*4+3]);
        }
    }
#pragma unroll
    for (int e = 0; e < E_; ++e) {
#pragma unroll
        for (int off = 32; off; off >>= 1) acc[e] += __shfl_xor(acc[e], off);
    }
    if (lane == 0) {
        float mx = acc[0];
#pragma unroll
        for (int e = 1; e < E_; ++e) mx = fmaxf(mx, acc[e]);
        float p[E_];
#pragma unroll
        for (int e = 0; e < E_; ++e) p[e] = expf(acc[e] - mx);
        float wsum = 0.f;
        int   bidx[K_]; float bval[K_];
        for (int k = 0; k < K_; ++k) {
            int bi = 0; float bv = -1.f;
            for (int e = 0; e < E_; ++e) {
                if (p[e] > bv) { bv = p[e]; bi = e; }
            }
            bidx[k] = bi; bval[k] = bv; wsum += bv; p[bi] = -2.f;
        }
        float inv = 1.f / wsum;
        for (int k = 0; k < K_; ++k) {
            topk_idx[t*K_ + k] = bidx[k];
            topk_w[t*K_ + k]   = bval[k] * inv;
        }
    }
}

// ---------------- Bucket ------------------------------------------------------
__global__ __launch_bounds__(256) void bucket_kernel(
    const int* __restrict__ topk_idx, const float* __restrict__ topk_w,
    int* __restrict__ cnt, int* __restrict__ off,
    int* __restrict__ row_token, float* __restrict__ row_w,
    int* __restrict__ pair2row)
{
    __shared__ int c1[E_], c2[E_], so[E_];
    int tid = threadIdx.x;
    if (tid < E_) { c1[tid] = 0; c2[tid] = 0; }
    __syncthreads();
    for (int p = tid; p < T_*K_; p += 256) atomicAdd(&c1[topk_idx[p]], 1);
    __syncthreads();
    if (tid == 0) {
        int o = 0;
        for (int e = 0; e < E_; ++e) { so[e] = o; off[e] = o; cnt[e] = c1[e]; o += c1[e]; }
    }
    __syncthreads();
    for (int p = tid; p < T_*K_; p += 256) {
        int e = topk_idx[p];
        int pos = so[e] + atomicAdd(&c2[e], 1);
        row_token[pos] = p >> 2;
        row_w[pos]     = topk_w[p];
        pair2row[p]    = pos;
    }
}

// ---------------- Grouped GEMM, split-bf16 3-term MFMA -----------------------
// Tile: 64 rows x 128 cols, BK=32, 256 threads = 4 waves (1 rg x 4 ct).
// Each wave owns a 64x32 output strip = 2 (mt) x 1 tiles of 32x32.
// A: fragment-major LDS hi/lo planes (conflict-free b128, measured 0 conflicts).
// B: per-lane direct global fragment loads (128B-coalesced per half-wave);
//    no rg-duplication now (each col-tile owned by exactly one wave).
// Grid b = rt*(16*NY) + e*NY + y, rt-major (live blocks dispatch first);
// panel-sharing rt-siblings are 16*NY apart (192/256, both ≡0 mod 8) ->
// same XCD under round-robin -> B panel L2 reuse (FETCH ~= weights once,
// verified round 7).
// MODE 0: block cols = [64 gate | 64 up] (waves 0,1 gate / 2,3 up);
//         epilogue silu(g)*u via LDS exchange -> h.  NY = F/64 = 12.
// MODE 1: plain 128 cols of wd; epilogue scales by row_w -> eo. NY = 16.
template<int MODE>
__global__ __launch_bounds__(256, 4) void moe_gemm(
    const float* __restrict__ A,
    const float* __restrict__ B,
    const int* __restrict__ cnt, const int* __restrict__ off,
    const int* __restrict__ row_token, const float* __restrict__ row_w,
    float* __restrict__ C)
{
    constexpr int KT = MODE ? F_ : D_;
    constexpr int NT = MODE ? D_ : 2*F_;
    constexpr int NY = MODE ? (D_/128) : (F_/64);

    const int b  = blockIdx.x;
    const int y  = b % NY;
    const int e  = (b / NY) & 15;
    const int rt = b / (NY * 16);      // rt-major: live blocks dispatch first
    const int n  = cnt[e];
    if (rt * 64 >= n) return;
    const int base = off[e];

    // A planes, fragment-major: [kchunk 0..3][row 0..63] of 8 bf16 (uint4)
    __shared__ uint4 Ah[4][64];
    __shared__ uint4 Al[4][64];
    __shared__ float u_lds[(MODE == 0) ? 64 : 1][(MODE == 0) ? 64 : 1];

    const int tid  = threadIdx.x;
    const int lane = tid & 63;
    const int wv   = tid >> 6;         // ct 0..3 (col strip)
    const int lrow = lane & 31;
    const int lhi  = lane >> 5;        // k-half selector

    // ---- staging: thread covers row tid&63, k-chunk tid>>6 (8 floats)
    const int r_s = tid & 63;
    const int kc  = tid >> 6;
    const int rl  = min(rt*64 + r_s, n - 1);
    const float* arow = MODE ? (A + (size_t)(base + rl) * F_)
                             : (A + (size_t)row_token[base + rl] * D_);

    // ---- B per-lane fragment column (one 32-col tile per wave)
    const float* Bbase = B + (size_t)e * KT * NT;
    int bcol;
    if (MODE) bcol = y*128 + wv*32 + lrow;
    else      bcol = ((wv < 2) ? (y*64 + wv*32) : (F_ + y*64 + (wv - 2)*32)) + lrow;

    f32x16 acc[2] = {};                // [mt]

    // prologue: preload A regs for k0=0
    float a_reg[8];
    {
        const float* p = arow + kc*8;
        float4 v0 = *(const float4*)(p);
        float4 v1 = *(const float4*)(p + 4);
        a_reg[0]=v0.x; a_reg[1]=v0.y; a_reg[2]=v0.z; a_reg[3]=v0.w;
        a_reg[4]=v1.x; a_reg[5]=v1.y; a_reg[6]=v1.z; a_reg[7]=v1.w;
    }

    for (int k0 = 0; k0 < KT; k0 += 32) {
        // ---- issue B fragment loads (per-lane; lanes 0..31 one 128B segment)
        float bfv[2][8];               // [kb][j]
        {
            const float* bp = Bbase + (size_t)(k0 + lhi*8) * NT + bcol;
#pragma unroll
            for (int kb = 0; kb < 2; ++kb)
#pragma unroll
                for (int j = 0; j < 8; ++j)
                    bfv[kb][j] = bp[(size_t)(kb*16 + j) * NT];
        }

        // ---- convert A regs -> split planes, store to LDS
        V8 hh, ll;
        split8(a_reg, hh.u, ll.u);
        __syncthreads();               // WAR: prior frag reads done
        Ah[kc][r_s] = hh.u;  Al[kc][r_s] = ll.u;

        // ---- prefetch next A k-slab into regs
        if (k0 + 32 < KT) {
            const float* p = arow + (k0 + 32) + kc*8;
            float4 v0 = *(const float4*)(p);
            float4 v1 = *(const float4*)(p + 4);
            a_reg[0]=v0.x; a_reg[1]=v0.y; a_reg[2]=v0.z; a_reg[3]=v0.w;
            a_reg[4]=v1.x; a_reg[5]=v1.y; a_reg[6]=v1.z; a_reg[7]=v1.w;
        }
        __syncthreads();               // RAW: LDS writes visible

        // ---- compute: 2 k-substeps x 2 mt x 3 split terms
#pragma unroll
        for (int kb = 0; kb < 2; ++kb) {
            V8 fah[2], fal[2];
#pragma unroll
            for (int mt = 0; mt < 2; ++mt) {
                int r = mt*32 + lrow;
                fah[mt].u = Ah[kb*2 + lhi][r];
                fal[mt].u = Al[kb*2 + lhi][r];
            }
            V8 bh, bl;
            split8(bfv[kb], bh.u, bl.u);
#pragma unroll
            for (int mt = 0; mt < 2; ++mt) {
                acc[mt] = __builtin_amdgcn_mfma_f32_32x32x16_bf16(fah[mt].v, bh.v, acc[mt], 0, 0, 0);
                acc[mt] = __builtin_amdgcn_mfma_f32_32x32x16_bf16(fah[mt].v, bl.v, acc[mt], 0, 0, 0);
                acc[mt] = __builtin_amdgcn_mfma_f32_32x32x16_bf16(fal[mt].v, bh.v, acc[mt], 0, 0, 0);
            }
        }
    }

    // ---- epilogue.  C/D frag: col = lane&31, row = (r&3) + 8*(r>>2) + 4*lhi
    if (MODE == 0) {
        // up waves (wv=2,3) publish u; gate waves (wv=0,1) compute silu(g)*u
        if (wv >= 2) {
#pragma unroll
            for (int mt = 0; mt < 2; ++mt)
#pragma unroll
                for (int r = 0; r < 16; ++r) {
                    int rowd = (r & 3) + 8*(r >> 2) + 4*lhi;
                    u_lds[mt*32 + rowd][(wv - 2)*32 + lrow] = acc[mt][r];
                }
        }
        __syncthreads();
        if (wv < 2) {
#pragma unroll
            for (int mt = 0; mt < 2; ++mt)
#pragma unroll
                for (int r = 0; r < 16; ++r) {
                    int rowd = (r & 3) + 8*(r >> 2) + 4*lhi;
                    int R = rt*64 + mt*32 + rowd;
                    if (R < n) {
                        float g = acc[mt][r];
                        float u = u_lds[mt*32 + rowd][wv*32 + lrow];
                        float s = g / (1.f + expf(-g)) * u;
                        C[(size_t)(base + R) * F_ + y*64 + wv*32 + lrow] = s;
                    }
                }
        }
    } else {
#pragma unroll
        for (int mt = 0; mt < 2; ++mt)
#pragma unroll
            for (int r = 0; r < 16; ++r) {
                int rowd = (r & 3) + 8*(r >> 2) + 4*lhi;
                int R = rt*64 + mt*32 + rowd;
                if (R < n) {
                    float w = row_w[base + R];
                    C[(size_t)(base + R) * D_ + y*128 + wv*32 + lrow] = acc[mt][r] * w;
                }
            }
    }
}

// ---------------- Combine: out[t] = sum_k eo[pair2row[t,k]] ------------------
__global__ __launch_bounds__(256) void combine_kernel(
    const float* __restrict__ eo, const int* __restrict__ pair2row,
    float* __restrict__ out)
{
    int idx = blockIdx.x * 256 + threadIdx.x;   // float4 index
    int t  = idx / (D_/4);
    int dc = idx % (D_/4);
    const int* pr = pair2row + t * K_;
    float4 s = {0.f, 0.f, 0.f, 0.f};
#pragma unroll
    for (int k = 0; k < K_; ++k) {
        float4 v = *(const float4*)(eo + (size_t)pr[k] * D_ + (size_t)dc * 4);
        s.x += v.x; s.y += v.y; s.z += v.z; s.w += v.w;
    }
    *(float4*)(out + (size_t)t * D_ + (size_t)dc * 4) = s;
}

extern "C" void kernel_launch(void* const* d_in, const int* in_sizes, int n_in,
                              void* d_out, int out_size, void* d_ws, size_t ws_size,
                              hipStream_t stream)
{
    (void)in_sizes; (void)n_in; (void)out_size; (void)ws_size;
    const float* x   = (const float*)d_in[0];   // (T, D)
    const float* gw  = (const float*)d_in[1];   // (D, E)
    const float* wgu = (const float*)d_in[2];   // (E, D, 2F)
    const float* wd  = (const float*)d_in[3];   // (E, F, D)
    float* out = (float*)d_out;                 // (T, D)

    char* w = (char*)d_ws;
    int*   topk_idx  = (int*)w;   w += (size_t)T_*K_*4;
    float* topk_w    = (float*)w; w += (size_t)T_*K_*4;
    int*   cnt       = (int*)w;   w += 64*4;
    int*   off       = (int*)w;   w += 64*4;
    int*   row_token = (int*)w;   w += (size_t)T_*K_*4;
    float* row_w     = (float*)w; w += (size_t)T_*K_*4;
    int*   pair2row  = (int*)w;   w += (size_t)T_*K_*4;
    uintptr_t up = ((uintptr_t)w + 255) & ~(uintptr_t)255;
    w = (char*)up;
    float* h  = (float*)w; w += (size_t)NR_*F_*4;      // 12.6 MB
    float* eo = (float*)w; w += (size_t)NR_*D_*4;      // 33.6 MB

    router_kernel<<<T_, 64, 0, stream>>>(x, gw, topk_idx, topk_w);
    bucket_kernel<<<1, 256, 0, stream>>>(topk_idx, topk_w, cnt, off,
                                         row_token, row_w, pair2row);
    moe_gemm<0><<<16 * 16 * (F_/64), 256, 0, stream>>>(
        x, wgu, cnt, off, row_token, row_w, h);
    moe_gemm<1><<<16 * 16 * (D_/128), 256, 0, stream>>>(
        h, wd, cnt, off, row_token, row_w, eo);
    combine_kernel<<<(T_*D_/4)/256, 256, 0, stream>>>(eo, pair2row, out);
}